// Round 7
// baseline (660.760 us; speedup 1.0000x reference)
//
#include <hip/hip_runtime.h>
#include <hip/hip_cooperative_groups.h>
#include <math.h>
#include <limits.h>

namespace cg = cooperative_groups;

// Problem constants (from reference): N=2e6, C=64, B=16, H=32.
#define NCH   64
#define NBAT  16
#define NHID  32
#define NGRP  4      // segment groups; 4 segments ~ 128 MB of x, fits L3
#define SPG   4      // segments per group (NBAT/NGRP)
#define NT    512    // threads per block (8 waves); LDS ~38KB -> 4 blocks/CU
#define RS    (NT / 16)   // rows in flight per block = 32

typedef float f4 __attribute__((ext_vector_type(4)));

// Workspace layout (floats):
//   [0    .. 1023]  per-(b,c) sums
//   [1024 .. 2047]  per-(b,c) maxes
//   [2048 .. 2063]  per-b counts
//   [3088 .. 3103]  (as int) seg_start[b], INT_MAX if empty

__device__ __forceinline__ void atomicMaxF(float* addr, float v) {
    // Monotone-lattice trick: works for mixed signs, init must be -inf.
    if (v >= 0.0f) atomicMax((int*)addr, __float_as_int(v));
    else           atomicMin((unsigned int*)addr, __float_as_uint(v));
}

__device__ __forceinline__ int minseg(const int* ss, int k, int n) {
    int m = n;
    for (int b = k; b < NBAT; ++b) m = min(m, ss[b]);
    return m;
}

__device__ __forceinline__ f4 vmax4(f4 a, f4 b) {
    f4 r;
    r.x = fmaxf(a.x, b.x); r.y = fmaxf(a.y, b.y);
    r.z = fmaxf(a.z, b.z); r.w = fmaxf(a.w, b.w);
    return r;
}

__device__ __forceinline__ void flush_seg(float* __restrict__ wsum,
                                          float* __restrict__ wmax,
                                          float* __restrict__ wcnt,
                                          int b, int c4,
                                          const f4& s, const f4& m, float cnt) {
    float* ps = wsum + b * NCH + c4 * 4;
    atomicAdd(ps + 0, s.x);
    atomicAdd(ps + 1, s.y);
    atomicAdd(ps + 2, s.z);
    atomicAdd(ps + 3, s.w);
    float* pm = wmax + b * NCH + c4 * 4;
    atomicMaxF(pm + 0, m.x);
    atomicMaxF(pm + 1, m.y);
    atomicMaxF(pm + 2, m.z);
    atomicMaxF(pm + 3, m.w);
    if (c4 == 0) atomicAdd(wcnt + b, cnt);
}

__global__ __launch_bounds__(NT, 8) void fused_kernel(
        const float* __restrict__ x, const int* __restrict__ bid,
        const float* __restrict__ W1, const float* __restrict__ b1,
        const float* __restrict__ W2, const float* __restrict__ b2,
        float* __restrict__ out, float* __restrict__ ws, int n) {
    cg::grid_group grid = cg::this_grid();
    const int t   = threadIdx.x;
    const int blk = blockIdx.x;
    const int nblk = gridDim.x;

    // LDS (~38 KB): combine buffers (reused as MLP scratch), weights, scales.
    __shared__ f4    ls[NT];
    __shared__ f4    lm[NT];
    __shared__ int   lb[NT];
    __shared__ float lc[NT];
    __shared__ float sW1[NHID * NCH];
    __shared__ float sW2[NCH * NHID];
    __shared__ float sb1[NHID];
    __shared__ float sb2[NCH];
    __shared__ float sscale[SPG * NCH];

    float* wsum = ws;
    float* wmax = ws + 1024;
    float* wcnt = ws + 2048;
    int*   ss   = (int*)(ws + 3088);

    // Stage weights once (L3-broadcast, 16 KB).
    for (int i = t; i < NHID * NCH; i += NT) { sW1[i] = W1[i]; sW2[i] = W2[i]; }
    if (t < NHID) sb1[t] = b1[t];
    if (t < NCH)  sb2[t] = b2[t];

    // Init stats + segment-start table (block 0), then make visible.
    if (blk == 0) {
        for (int i = t; i < 1024; i += NT) { wsum[i] = 0.0f; wmax[i] = -INFINITY; }
        if (t < NBAT) wcnt[t] = 0.0f;
        if (t < NBAT) ss[t] = INT_MAX;
    }
    grid.sync();

    // Scan sorted batch_ids for segment starts.
    for (int i = blk * NT + t; i < n; i += nblk * NT) {
        const int b = bid[i];
        if (i == 0) atomicMin(&ss[b], 0);
        else if (bid[i - 1] != b) atomicMin(&ss[b], i);
    }
    grid.sync();

    const int c4 = t & 15;   // channel group (float4)
    const int rg = t >> 4;   // row group (RS rows in flight)
    const f4 fzero = {0.f, 0.f, 0.f, 0.f};
    const f4 fninf = {-INFINITY, -INFINITY, -INFINITY, -INFINITY};

    for (int g = 0; g < NGRP; ++g) {
        const int gb = min(minseg(ss, g * SPG, n), n);
        const int ge = min(minseg(ss, g * SPG + SPG, n), n);
        const int rows = ge - gb;
        const int rpb  = rows > 0 ? (rows + nblk - 1) / nblk : 0;
        const int r0   = gb + blk * rpb;
        const int rend = min(r0 + rpb, ge);

        // ---- pool own slice (x2 unrolled: 2 independent 1KB wave-loads) ----
        int cur = -1;
        f4 s = fzero, m = fninf;
        float cnt = 0.0f;
        auto acc = [&](int b, const f4& v) {
            if (b != cur) {
                if (cur >= 0) flush_seg(wsum, wmax, wcnt, cur, c4, s, m, cnt);
                cur = b; s = fzero; m = fninf; cnt = 0.0f;
            }
            s += v; m = vmax4(m, v); cnt += 1.0f;
        };
        int r = r0 + rg;
        for (; r + RS < rend; r += 2 * RS) {
            const int b0 = bid[r];
            const int b1i = bid[r + RS];
            const f4 v0 = *reinterpret_cast<const f4*>(x + (size_t)r * NCH + c4 * 4);
            const f4 v1 = *reinterpret_cast<const f4*>(x + (size_t)(r + RS) * NCH + c4 * 4);
            acc(b0, v0);
            acc(b1i, v1);
        }
        for (; r < rend; r += RS) {
            const int b = bid[r];
            const f4 v = *reinterpret_cast<const f4*>(x + (size_t)r * NCH + c4 * 4);
            acc(b, v);
        }
        // Block combine across the RS row groups (same c4).
        lb[t] = cur; ls[t] = s; lm[t] = m; lc[t] = cnt;
        __syncthreads();
        if (rg == 0) {
            for (int gg = 1; gg < RS; ++gg) {
                const int i = gg * 16 + c4;
                const int ob = lb[i];
                if (ob < 0) continue;
                if (ob == cur && cur >= 0) {
                    s += ls[i]; m = vmax4(m, lm[i]); cnt += lc[i];
                } else if (cur < 0) {
                    cur = ob; s = ls[i]; m = lm[i]; cnt = lc[i];
                } else {
                    flush_seg(wsum, wmax, wcnt, ob, c4, ls[i], lm[i], lc[i]);
                }
            }
            if (cur >= 0) flush_seg(wsum, wmax, wcnt, cur, c4, s, m, cnt);
        }
        grid.sync();  // group-g stats complete, device-visible

        // ---- tiny MLP, redundant per block, in LDS (reuses ls region) ----
        float* avg = (float*)ls;          // 256 floats
        float* mxs = avg + SPG * NCH;     // 256
        float* h1a = mxs + SPG * NCH;     // 128
        float* h1m = h1a + SPG * NHID;    // 128
        if (t < SPG * NCH) {
            const int b = g * SPG + (t >> 6);
            const float c = wcnt[b];
            avg[t] = wsum[b * NCH + (t & 63)] / fmaxf(c, 1.0f);
            mxs[t] = wmax[b * NCH + (t & 63)];
        }
        __syncthreads();
        if (t < SPG * NHID) {
            const int bb = t >> 5, j = t & 31;
            float sa = sb1[j], sm = sb1[j];
            const float* w = &sW1[j * NCH];
            for (int c = 0; c < NCH; ++c) {
                const float wv = w[c];
                sa += avg[bb * NCH + c] * wv;
                sm += mxs[bb * NCH + c] * wv;
            }
            h1a[t] = fmaxf(sa, 0.0f);
            h1m[t] = fmaxf(sm, 0.0f);
        }
        __syncthreads();
        if (t < SPG * NCH) {
            const int bb = t >> 6, c = t & 63;
            float ya = sb2[c], ym = sb2[c];
            const float* w = &sW2[c * NHID];
            for (int j = 0; j < NHID; ++j) {
                const float wv = w[j];
                ya += h1a[bb * NHID + j] * wv;
                ym += h1m[bb * NHID + j] * wv;
            }
            const float z = ya + ym;
            sscale[t] = 1.0f + 1.0f / (1.0f + expf(-z));  // out = x*(1+att)
        }
        __syncthreads();

        // ---- apply own slice (rows just read by this CU -> L2/L3 hits) ----
        // scale index: bid in [4g, 4g+4) -> bid & 3 (groups are 4-aligned).
        r = r0 + rg;
        for (; r + RS < rend; r += 2 * RS) {
            const int b0 = bid[r] & 3;
            const int b1i = bid[r + RS] & 3;
            const f4 v0 = *reinterpret_cast<const f4*>(x + (size_t)r * NCH + c4 * 4);
            const f4 v1 = *reinterpret_cast<const f4*>(x + (size_t)(r + RS) * NCH + c4 * 4);
            const f4 s0 = *reinterpret_cast<const f4*>(&sscale[b0 * NCH + c4 * 4]);
            const f4 s1 = *reinterpret_cast<const f4*>(&sscale[b1i * NCH + c4 * 4]);
            const f4 o0 = v0 * s0;
            const f4 o1 = v1 * s1;
            __builtin_nontemporal_store(o0, reinterpret_cast<f4*>(out + (size_t)r * NCH + c4 * 4));
            __builtin_nontemporal_store(o1, reinterpret_cast<f4*>(out + (size_t)(r + RS) * NCH + c4 * 4));
        }
        for (; r < rend; r += RS) {
            const int b = bid[r] & 3;
            const f4 v  = *reinterpret_cast<const f4*>(x + (size_t)r * NCH + c4 * 4);
            const f4 sc = *reinterpret_cast<const f4*>(&sscale[b * NCH + c4 * 4]);
            const f4 o = v * sc;
            __builtin_nontemporal_store(o, reinterpret_cast<f4*>(out + (size_t)r * NCH + c4 * 4));
        }
        // grid.sync at next group's pool-end provides the cross-block fence;
        // sscale overwrite is gated by that sync too (all blocks past apply).
    }
}

extern "C" void kernel_launch(void* const* d_in, const int* in_sizes, int n_in,
                              void* d_out, int out_size, void* d_ws, size_t ws_size,
                              hipStream_t stream) {
    const float* x   = (const float*)d_in[0];
    const int*   bid = (const int*)d_in[1];
    const float* W1  = (const float*)d_in[2];
    const float* b1  = (const float*)d_in[3];
    const float* W2  = (const float*)d_in[4];
    const float* b2  = (const float*)d_in[5];
    float* out = (float*)d_out;
    float* ws  = (float*)d_ws;
    int n = in_sizes[1];  // N (batch_ids element count)

    // Max co-resident blocks (host-side query: capture-safe, deterministic).
    int occ = 0;
    if (hipOccupancyMaxActiveBlocksPerMultiprocessor(&occ, (const void*)fused_kernel,
                                                     NT, 0) != hipSuccess || occ < 1)
        occ = 1;
    const int nb = occ * 256;   // MI355X: 256 CUs

    void* args[] = { (void*)&x, (void*)&bid, (void*)&W1, (void*)&b1,
                     (void*)&W2, (void*)&b2, (void*)&out, (void*)&ws, (void*)&n };
    hipLaunchCooperativeKernel((const void*)fused_kernel, dim3(nb), dim3(NT),
                               args, 0, stream);
}

// Round 8
// 302.409 us; speedup vs baseline: 2.1850x; 2.1850x over previous
//
#include <hip/hip_runtime.h>
#include <math.h>

// Problem constants (from reference): N=2e6, C=64, B=16, H=32.
#define NCH   64
#define NBAT  16
#define NHID  32
#define NBLK  1024   // chunk count shared by pool and apply (1:1 mapping)

typedef float f4 __attribute__((ext_vector_type(4)));

// Workspace layout (floats):
//   [0    .. 1023]  per-(b,c) sums
//   [1024 .. 2047]  per-(b,c) maxes
//   [2064 .. 3087]  per-(b,c) scale = 1 + sigmoid(mlp(avg)+mlp(max))

__device__ __forceinline__ void atomicMaxF(float* addr, float v) {
    // Monotone-lattice trick: works for mixed signs, init must be -inf.
    // -inf is the identity (never corrupts an existing value).
    if (v >= 0.0f) atomicMax((int*)addr, __float_as_int(v));
    else           atomicMin((unsigned int*)addr, __float_as_uint(v));
}

__device__ __forceinline__ f4 vmax4(f4 a, f4 b) {
    f4 r;
    r.x = fmaxf(a.x, b.x); r.y = fmaxf(a.y, b.y);
    r.z = fmaxf(a.z, b.z); r.w = fmaxf(a.w, b.w);
    return r;
}

// First index i with a[i] >= v (a sorted ascending).
__device__ __forceinline__ int lower_bound_i(const int* __restrict__ a, int n, int v) {
    int lo = 0, hi = n;
    while (lo < hi) {
        const int mid = (lo + hi) >> 1;
        if (a[mid] < v) lo = mid + 1; else hi = mid;
    }
    return lo;
}

__global__ __launch_bounds__(256) void init_kernel(float* ws) {
    const int i = blockIdx.x * blockDim.x + threadIdx.x;
    if (i < 1024) {
        ws[i] = 0.0f;                  // sums
        ws[1024 + i] = -INFINITY;      // maxes
    }
}

// Segment-sum/max. Each block: contiguous row chunk; segment bounds from
// binary search (no bid loads, no branches in the hot loop). Thread layout:
// c4 = tid&15 (channel group of 4 via float4), rg = tid>>4 (16 rows in
// flight); x4 unroll -> 4 independent 1KB wave-loads in flight.
__global__ __launch_bounds__(256) void pool_kernel(const float* __restrict__ x,
                                                   const int* __restrict__ bid,
                                                   float* __restrict__ wsum,
                                                   float* __restrict__ wmax,
                                                   int n, int rpb) {
    __shared__ int sstart[NBAT + 1];
    __shared__ f4 ls[256];
    __shared__ f4 lm[256];
    const int t = threadIdx.x;
    if (t <= NBAT) sstart[t] = (t == NBAT) ? n : lower_bound_i(bid, n, t);
    __syncthreads();

    const int c4 = t & 15;
    const int rg = t >> 4;
    const int r0 = blockIdx.x * rpb;
    const int rend = min(r0 + rpb, n);
    const f4 fzero = {0.f, 0.f, 0.f, 0.f};
    const f4 fninf = {-INFINITY, -INFINITY, -INFINITY, -INFINITY};

    for (int b = 0; b < NBAT; ++b) {
        const int lo = max(sstart[b], r0);
        const int hi = min(sstart[b + 1], rend);
        if (lo >= hi) continue;                 // block-uniform

        f4 s = fzero, m = fninf;
        const int base = lo + rg;
        const int k = (hi > base) ? ((hi - base + 15) >> 4) : 0;
        const float* xp = x + (size_t)base * NCH + c4 * 4;
        int j = 0;
        for (; j + 4 <= k; j += 4) {
            const f4 v0 = *reinterpret_cast<const f4*>(xp + (size_t)(j + 0) * 16 * NCH);
            const f4 v1 = *reinterpret_cast<const f4*>(xp + (size_t)(j + 1) * 16 * NCH);
            const f4 v2 = *reinterpret_cast<const f4*>(xp + (size_t)(j + 2) * 16 * NCH);
            const f4 v3 = *reinterpret_cast<const f4*>(xp + (size_t)(j + 3) * 16 * NCH);
            s += v0; s += v1; s += v2; s += v3;
            m = vmax4(m, vmax4(vmax4(v0, v1), vmax4(v2, v3)));
        }
        for (; j < k; ++j) {
            const f4 v = *reinterpret_cast<const f4*>(xp + (size_t)j * 16 * NCH);
            s += v; m = vmax4(m, v);
        }

        // Block combine across the 16 row groups (same c4), then 8 atomics.
        ls[t] = s; lm[t] = m;
        __syncthreads();
        if (rg == 0) {
            for (int gg = 1; gg < 16; ++gg) {
                s += ls[gg * 16 + c4];
                m = vmax4(m, lm[gg * 16 + c4]);
            }
            float* ps = wsum + b * NCH + c4 * 4;
            atomicAdd(ps + 0, s.x);
            atomicAdd(ps + 1, s.y);
            atomicAdd(ps + 2, s.z);
            atomicAdd(ps + 3, s.w);
            float* pm = wmax + b * NCH + c4 * 4;
            atomicMaxF(pm + 0, m.x);
            atomicMaxF(pm + 1, m.y);
            atomicMaxF(pm + 2, m.z);
            atomicMaxF(pm + 3, m.w);
        }
        __syncthreads();   // ls/lm reused by next segment
    }
}

// Tiny MLP on pooled stats: one block, everything in LDS. Counts come from
// the segment bounds (binary search), not an accumulated counter.
__global__ __launch_bounds__(512) void mlp_kernel(const float* __restrict__ ws,
                                                  const int* __restrict__ bid,
                                                  const float* __restrict__ W1,
                                                  const float* __restrict__ b1,
                                                  const float* __restrict__ W2,
                                                  const float* __restrict__ b2,
                                                  float* __restrict__ scale_out,
                                                  int n) {
    __shared__ int   sstart[NBAT + 1];
    __shared__ float avg[NBAT * NCH];
    __shared__ float mxs[NBAT * NCH];
    __shared__ float h1a[NBAT * NHID];
    __shared__ float h1m[NBAT * NHID];
    const int t = threadIdx.x;
    if (t <= NBAT) sstart[t] = (t == NBAT) ? n : lower_bound_i(bid, n, t);
    __syncthreads();

    for (int i = t; i < NBAT * NCH; i += 512) {
        const int b = i >> 6;
        const float c = (float)(sstart[b + 1] - sstart[b]);
        avg[i] = ws[i] / fmaxf(c, 1.0f);
        mxs[i] = ws[1024 + i];
    }
    __syncthreads();

    {   // h1 = relu(h @ W1.T + b1), both branches. 512 threads = 16b x 32j.
        const int b = t >> 5, j = t & 31;
        float sa = b1[j], sm = b1[j];
        const float* w = W1 + j * NCH;
        for (int c = 0; c < NCH; ++c) {
            const float wv = w[c];
            sa += avg[b * NCH + c] * wv;
            sm += mxs[b * NCH + c] * wv;
        }
        h1a[b * NHID + j] = fmaxf(sa, 0.0f);
        h1m[b * NHID + j] = fmaxf(sm, 0.0f);
    }
    __syncthreads();

    for (int i = t; i < NBAT * NCH; i += 512) {
        const int b = i >> 6, c = i & 63;
        float ya = b2[c], ym = b2[c];
        const float* w = W2 + c * NHID;
        for (int j = 0; j < NHID; ++j) {
            const float wv = w[j];
            ya += h1a[b * NHID + j] * wv;
            ym += h1m[b * NHID + j] * wv;
        }
        const float z = ya + ym;
        const float sig = 1.0f / (1.0f + expf(-z));
        scale_out[i] = 1.0f + sig;  // out = x*att + x = x*(1+att)
    }
}

// out[r][c] = x[r][c] * scale[seg(r)][c]. Block i covers EXACTLY pool block
// i's chunk, traversed tail-first (reverse segments, descending row tiles):
// pool's blocks streamed in parallel, so L3 holds each chunk's tail; re-read
// it first. Scale is held in registers per segment (no bid loads, branch-
// free hot loop, x4 unroll). Nontemporal stores keep `out` out of L3.
__global__ __launch_bounds__(256) void apply_kernel(const float* __restrict__ x,
                                                    const int* __restrict__ bid,
                                                    const float* __restrict__ scale,
                                                    float* __restrict__ out,
                                                    int n, int rpb) {
    __shared__ int   sstart[NBAT + 1];
    __shared__ float s_scale[NBAT * NCH];
    const int t = threadIdx.x;
    if (t <= NBAT) sstart[t] = (t == NBAT) ? n : lower_bound_i(bid, n, t);
    for (int i = t; i < NBAT * NCH; i += 256) s_scale[i] = scale[i];
    __syncthreads();

    const int c4 = t & 15;
    const int rg = t >> 4;
    const int r0 = blockIdx.x * rpb;
    const int rend = min(r0 + rpb, n);

    for (int b = NBAT - 1; b >= 0; --b) {
        const int lo = max(sstart[b], r0);
        const int hi = min(sstart[b + 1], rend);
        if (lo >= hi) continue;                 // block-uniform

        const f4 sc = *reinterpret_cast<const f4*>(s_scale + b * NCH + c4 * 4);
        const int base = lo + rg;
        int k = (hi > base) ? ((hi - base + 15) >> 4) : 0;
        const float* xp = x + (size_t)base * NCH + c4 * 4;
        float* op = out + (size_t)base * NCH + c4 * 4;

        while (k >= 4) {
            k -= 4;
            const f4 v0 = *reinterpret_cast<const f4*>(xp + (size_t)(k + 0) * 16 * NCH);
            const f4 v1 = *reinterpret_cast<const f4*>(xp + (size_t)(k + 1) * 16 * NCH);
            const f4 v2 = *reinterpret_cast<const f4*>(xp + (size_t)(k + 2) * 16 * NCH);
            const f4 v3 = *reinterpret_cast<const f4*>(xp + (size_t)(k + 3) * 16 * NCH);
            __builtin_nontemporal_store(v0 * sc, reinterpret_cast<f4*>(op + (size_t)(k + 0) * 16 * NCH));
            __builtin_nontemporal_store(v1 * sc, reinterpret_cast<f4*>(op + (size_t)(k + 1) * 16 * NCH));
            __builtin_nontemporal_store(v2 * sc, reinterpret_cast<f4*>(op + (size_t)(k + 2) * 16 * NCH));
            __builtin_nontemporal_store(v3 * sc, reinterpret_cast<f4*>(op + (size_t)(k + 3) * 16 * NCH));
        }
        while (k > 0) {
            --k;
            const f4 v = *reinterpret_cast<const f4*>(xp + (size_t)k * 16 * NCH);
            __builtin_nontemporal_store(v * sc, reinterpret_cast<f4*>(op + (size_t)k * 16 * NCH));
        }
    }
}

extern "C" void kernel_launch(void* const* d_in, const int* in_sizes, int n_in,
                              void* d_out, int out_size, void* d_ws, size_t ws_size,
                              hipStream_t stream) {
    const float* x   = (const float*)d_in[0];
    const int*   bid = (const int*)d_in[1];
    const float* W1  = (const float*)d_in[2];
    const float* b1  = (const float*)d_in[3];
    const float* W2  = (const float*)d_in[4];
    const float* b2  = (const float*)d_in[5];
    float* out = (float*)d_out;
    const int n = in_sizes[1];  // N (batch_ids element count)

    float* ws     = (float*)d_ws;
    float* wsum   = ws;
    float* wmax   = ws + 1024;
    float* wscale = ws + 2064;

    hipLaunchKernelGGL(init_kernel, dim3(4), dim3(256), 0, stream, ws);

    const int rpb = (n + NBLK - 1) / NBLK;
    hipLaunchKernelGGL(pool_kernel, dim3(NBLK), dim3(256), 0, stream,
                       x, bid, wsum, wmax, n, rpb);

    hipLaunchKernelGGL(mlp_kernel, dim3(1), dim3(512), 0, stream,
                       ws, bid, W1, b1, W2, b2, wscale, n);

    hipLaunchKernelGGL(apply_kernel, dim3(NBLK), dim3(256), 0, stream,
                       x, bid, wscale, out, n, rpb);
}